// Round 1
// baseline (2936.697 us; speedup 1.0000x reference)
//
#include <hip/hip_runtime.h>
#include <math.h>

#define N_NODES 100000
#define N_EDGES 800000
#define F 128

// ---------------- degree / normalization ----------------

__global__ void k_init_deg(float* __restrict__ deg) {
    int i = blockIdx.x * blockDim.x + threadIdx.x;
    if (i < N_NODES) deg[i] = 1.0f;   // self-loop contributes 1
}

__global__ void k_count_deg(const int* __restrict__ col, float* __restrict__ deg) {
    int e = blockIdx.x * blockDim.x + threadIdx.x;
    if (e < N_EDGES) {
        int c = col[e];
        if ((unsigned)c < N_NODES) atomicAdd(&deg[c], 1.0f);
    }
}

__global__ void k_rsqrt_deg(float* __restrict__ deg) {
    int i = blockIdx.x * blockDim.x + threadIdx.x;
    if (i < N_NODES) deg[i] = rsqrtf(deg[i]);   // deg >= 1 always
}

// ---------------- propagation ----------------

// dst[i,:] = dinv[i]^2 * src[i,:]   (self-loop term; also serves as zero-init)
__global__ void k_selfloop(const float* __restrict__ src, const float* __restrict__ dinv,
                           float* __restrict__ dst) {
    int idx = blockIdx.x * blockDim.x + threadIdx.x;   // over N*F/4 float4s
    const int total = N_NODES * (F / 4);
    if (idx < total) {
        int node = idx >> 5;  // F/4 == 32
        float s = dinv[node]; s *= s;
        float4 v = ((const float4*)src)[idx];
        v.x *= s; v.y *= s; v.z *= s; v.w *= s;
        ((float4*)dst)[idx] = v;
    }
}

// dst[c,:] += dinv[r]*dinv[c] * src[r,:]  for each edge; 32 lanes/edge, float4/lane
__global__ void k_scatter(const int* __restrict__ row, const int* __restrict__ col,
                          const float* __restrict__ dinv,
                          const float* __restrict__ src, float* __restrict__ dst) {
    int gid = blockIdx.x * blockDim.x + threadIdx.x;
    int e = gid >> 5;
    int lane = gid & 31;
    if (e >= N_EDGES) return;
    int r = row[e], c = col[e];
    if ((unsigned)r >= N_NODES || (unsigned)c >= N_NODES) return;  // robustness guard
    float w = dinv[r] * dinv[c];
    float4 v = ((const float4*)(src + (size_t)r * F))[lane];
    float* d = dst + (size_t)c * F + lane * 4;
    atomicAdd(d + 0, w * v.x);
    atomicAdd(d + 1, w * v.y);
    atomicAdd(d + 2, w * v.z);
    atomicAdd(d + 3, w * v.w);
}

// ---------------- fused GEMM + bias + log_softmax (in-place) ----------------

#define NODES_PER_GROUP 16

__global__ __launch_bounds__(256, 2) void k_gemm_lsm(float* __restrict__ h,
                                                     const float* __restrict__ W,
                                                     const float* __restrict__ b) {
    __shared__ float Wt[128 * 129];                 // Wt[k*129+o] = W[o*128+k], padded
    __shared__ float hbuf[NODES_PER_GROUP * F];

    for (int idx = threadIdx.x; idx < 128 * 128; idx += 256) {
        int o = idx >> 7, k = idx & 127;
        Wt[k * 129 + o] = W[idx];                   // (k+o)%32 banks -> conflict-free
    }

    int lane = threadIdx.x & 31;
    int pair = threadIdx.x >> 5;                    // 0..7 -> node pair within group
    float bv[4];
#pragma unroll
    for (int j = 0; j < 4; ++j) bv[j] = b[lane + 32 * j];

    const int ngroups = N_NODES / NODES_PER_GROUP;  // 6250, exact
    for (int g = blockIdx.x; g < ngroups; g += gridDim.x) {
        int base = g * NODES_PER_GROUP;
        __syncthreads();                            // hbuf (and Wt first iter) ready/reusable
        const float4* src = (const float4*)(h + (size_t)base * F);
        float4* hb4 = (float4*)hbuf;
        for (int idx = threadIdx.x; idx < NODES_PER_GROUP * F / 4; idx += 256)
            hb4[idx] = src[idx];
        __syncthreads();

        int nA = pair * 2, nB = pair * 2 + 1;
        float accA[4], accB[4];
#pragma unroll
        for (int j = 0; j < 4; ++j) { accA[j] = bv[j]; accB[j] = bv[j]; }
        const float* hA = hbuf + nA * F;
        const float* hB = hbuf + nB * F;
        for (int k = 0; k < F; ++k) {
            float ha = hA[k], hb = hB[k];
            const float* wrow = Wt + k * 129 + lane;
#pragma unroll
            for (int j = 0; j < 4; ++j) {
                float w = wrow[32 * j];
                accA[j] = fmaf(w, ha, accA[j]);
                accB[j] = fmaf(w, hb, accB[j]);
            }
        }

        // log_softmax over 128 outputs = 4 regs x 32 lanes
        float mA = fmaxf(fmaxf(accA[0], accA[1]), fmaxf(accA[2], accA[3]));
        float mB = fmaxf(fmaxf(accB[0], accB[1]), fmaxf(accB[2], accB[3]));
#pragma unroll
        for (int s = 1; s < 32; s <<= 1) {
            mA = fmaxf(mA, __shfl_xor(mA, s, 32));
            mB = fmaxf(mB, __shfl_xor(mB, s, 32));
        }
        float sA = 0.f, sB = 0.f;
#pragma unroll
        for (int j = 0; j < 4; ++j) {
            sA += __expf(accA[j] - mA);
            sB += __expf(accB[j] - mB);
        }
#pragma unroll
        for (int s = 1; s < 32; s <<= 1) {
            sA += __shfl_xor(sA, s, 32);
            sB += __shfl_xor(sB, s, 32);
        }
        float lA = mA + __logf(sA);
        float lB = mB + __logf(sB);
        float* outA = h + (size_t)(base + nA) * F;
        float* outB = h + (size_t)(base + nB) * F;
#pragma unroll
        for (int j = 0; j < 4; ++j) {
            outA[lane + 32 * j] = accA[j] - lA;
            outB[lane + 32 * j] = accB[j] - lB;
        }
    }
}

// ---------------- launch ----------------

extern "C" void kernel_launch(void* const* d_in, const int* in_sizes, int n_in,
                              void* d_out, int out_size, void* d_ws, size_t ws_size,
                              hipStream_t stream) {
    const float* x = (const float*)d_in[0];
    const float* W = (const float*)d_in[1];
    const float* b = (const float*)d_in[2];
    const int* edge = (const int*)d_in[3];
    const int* row = edge;             // source nodes j
    const int* col = edge + N_EDGES;   // target nodes i
    float* out = (float*)d_out;

    float* deg = (float*)d_ws;                 // N floats (reused as dinv)
    float* h1  = deg + 131072;                 // N*F floats, 512KB-aligned offset

    k_init_deg<<<(N_NODES + 255) / 256, 256, 0, stream>>>(deg);
    k_count_deg<<<(N_EDGES + 255) / 256, 256, 0, stream>>>(col, deg);
    k_rsqrt_deg<<<(N_NODES + 255) / 256, 256, 0, stream>>>(deg);

    int sl_blocks = (N_NODES * (F / 4) + 255) / 256;
    int sc_blocks = (N_EDGES * 32) / 256;      // exact: 100000

    // hop 1: x -> h1
    k_selfloop<<<sl_blocks, 256, 0, stream>>>(x, deg, h1);
    k_scatter<<<sc_blocks, 256, 0, stream>>>(row, col, deg, x, h1);
    // hop 2: h1 -> out
    k_selfloop<<<sl_blocks, 256, 0, stream>>>(h1, deg, out);
    k_scatter<<<sc_blocks, 256, 0, stream>>>(row, col, deg, h1, out);
    // fused linear + log_softmax, in place on out
    k_gemm_lsm<<<512, 256, 0, stream>>>(out, W, b);
}

// Round 2
// 409.025 us; speedup vs baseline: 7.1798x; 7.1798x over previous
//
#include <hip/hip_runtime.h>
#include <math.h>

#define N_NODES 100000
#define N_EDGES 800000
#define F 128
#define SCAN_BLOCKS ((N_NODES + 255) / 256)   // 391

// ---------------- CSR build ----------------

__global__ void k_zero(int* __restrict__ p, int n) {
    int i = blockIdx.x * blockDim.x + threadIdx.x;
    if (i < n) p[i] = 0;
}

__global__ void k_hist(const int* __restrict__ col, int* __restrict__ cnt) {
    int e = blockIdx.x * blockDim.x + threadIdx.x;
    if (e < N_EDGES) atomicAdd(&cnt[col[e]], 1);
}

__global__ void k_dinv(const int* __restrict__ cnt, float* __restrict__ dinv) {
    int i = blockIdx.x * blockDim.x + threadIdx.x;
    if (i < N_NODES) dinv[i] = rsqrtf((float)cnt[i] + 1.0f);  // +1 self-loop
}

// block-local exclusive scan of cnt -> rowptr, block totals -> bsum
__global__ void k_scan1(const int* __restrict__ cnt, int* __restrict__ rowptr,
                        int* __restrict__ bsum) {
    __shared__ int s[256];
    int t = threadIdx.x, i = blockIdx.x * 256 + t;
    int v = (i < N_NODES) ? cnt[i] : 0;
    s[t] = v; __syncthreads();
#pragma unroll
    for (int off = 1; off < 256; off <<= 1) {
        int u = (t >= off) ? s[t - off] : 0;
        __syncthreads();
        s[t] += u; __syncthreads();
    }
    if (i < N_NODES) rowptr[i] = s[t] - v;      // exclusive
    if (t == 255) bsum[blockIdx.x] = s[255];
}

// exclusive scan of the 391 block sums, single block of 512
__global__ void k_scan2(int* __restrict__ bsum) {
    __shared__ int s[512];
    int t = threadIdx.x;
    int v = (t < SCAN_BLOCKS) ? bsum[t] : 0;
    s[t] = v; __syncthreads();
#pragma unroll
    for (int off = 1; off < 512; off <<= 1) {
        int u = (t >= off) ? s[t - off] : 0;
        __syncthreads();
        s[t] += u; __syncthreads();
    }
    if (t < SCAN_BLOCKS) bsum[t] = s[t] - v;    // exclusive
}

__global__ void k_scan3(int* __restrict__ rowptr, const int* __restrict__ bsum) {
    int i = blockIdx.x * blockDim.x + threadIdx.x;
    if (i < N_NODES) rowptr[i] += bsum[i >> 8];
    if (i == 0) rowptr[N_NODES] = N_EDGES;
}

__global__ void k_fill(const int* __restrict__ row, const int* __restrict__ col,
                       const int* __restrict__ rowptr, int* __restrict__ fill,
                       const float* __restrict__ dinv,
                       int* __restrict__ csr_src, float* __restrict__ csr_w) {
    int e = blockIdx.x * blockDim.x + threadIdx.x;
    if (e >= N_EDGES) return;
    int r = row[e], c = col[e];
    int pos = rowptr[c] + atomicAdd(&fill[c], 1);
    csr_src[pos] = r;
    csr_w[pos] = dinv[r] * dinv[c];
}

// ---------------- propagation: pure gather, one wave64 per node ----------------

__global__ __launch_bounds__(256) void k_gather(const int* __restrict__ rowptr,
                                                const int* __restrict__ csr_src,
                                                const float* __restrict__ csr_w,
                                                const float* __restrict__ dinv,
                                                const float* __restrict__ src,
                                                float* __restrict__ dst) {
    int node = (blockIdx.x * blockDim.x + threadIdx.x) >> 6;
    int lane = threadIdx.x & 63;
    if (node >= N_NODES) return;
    const float2* s2 = (const float2*)src;
    float s = dinv[node];
    float2 acc = s2[(size_t)node * 64 + lane];
    float ss = s * s;                            // self-loop term
    acc.x *= ss; acc.y *= ss;
    int beg = rowptr[node], end = rowptr[node + 1];
    int e = beg;
    for (; e + 2 <= end; e += 2) {               // 2-edge unroll for load ILP
        int r0 = csr_src[e], r1 = csr_src[e + 1];
        float w0 = csr_w[e], w1 = csr_w[e + 1];
        float2 u0 = s2[(size_t)r0 * 64 + lane];
        float2 u1 = s2[(size_t)r1 * 64 + lane];
        acc.x = fmaf(w0, u0.x, acc.x); acc.y = fmaf(w0, u0.y, acc.y);
        acc.x = fmaf(w1, u1.x, acc.x); acc.y = fmaf(w1, u1.y, acc.y);
    }
    if (e < end) {
        int r0 = csr_src[e]; float w0 = csr_w[e];
        float2 u0 = s2[(size_t)r0 * 64 + lane];
        acc.x = fmaf(w0, u0.x, acc.x); acc.y = fmaf(w0, u0.y, acc.y);
    }
    ((float2*)dst)[(size_t)node * 64 + lane] = acc;
}

// ---------------- fused GEMM + bias + log_softmax (in-place) ----------------

#define NODES_PER_GROUP 16

__global__ __launch_bounds__(256, 2) void k_gemm_lsm(float* __restrict__ h,
                                                     const float* __restrict__ W,
                                                     const float* __restrict__ b) {
    __shared__ float Wt[128 * 129];                 // Wt[k*129+o] = W[o*128+k], padded
    __shared__ float hbuf[NODES_PER_GROUP * F];

    for (int idx = threadIdx.x; idx < 128 * 128; idx += 256) {
        int o = idx >> 7, k = idx & 127;
        Wt[k * 129 + o] = W[idx];
    }

    int lane = threadIdx.x & 31;
    int pair = threadIdx.x >> 5;
    float bv[4];
#pragma unroll
    for (int j = 0; j < 4; ++j) bv[j] = b[lane + 32 * j];

    const int ngroups = N_NODES / NODES_PER_GROUP;  // 6250, exact
    for (int g = blockIdx.x; g < ngroups; g += gridDim.x) {
        int base = g * NODES_PER_GROUP;
        __syncthreads();
        const float4* src = (const float4*)(h + (size_t)base * F);
        float4* hb4 = (float4*)hbuf;
        for (int idx = threadIdx.x; idx < NODES_PER_GROUP * F / 4; idx += 256)
            hb4[idx] = src[idx];
        __syncthreads();

        int nA = pair * 2, nB = pair * 2 + 1;
        float accA[4], accB[4];
#pragma unroll
        for (int j = 0; j < 4; ++j) { accA[j] = bv[j]; accB[j] = bv[j]; }
        const float* hA = hbuf + nA * F;
        const float* hB = hbuf + nB * F;
        for (int k = 0; k < F; ++k) {
            float ha = hA[k], hb = hB[k];
            const float* wrow = Wt + k * 129 + lane;
#pragma unroll
            for (int j = 0; j < 4; ++j) {
                float w = wrow[32 * j];
                accA[j] = fmaf(w, ha, accA[j]);
                accB[j] = fmaf(w, hb, accB[j]);
            }
        }

        float mA = fmaxf(fmaxf(accA[0], accA[1]), fmaxf(accA[2], accA[3]));
        float mB = fmaxf(fmaxf(accB[0], accB[1]), fmaxf(accB[2], accB[3]));
#pragma unroll
        for (int s = 1; s < 32; s <<= 1) {
            mA = fmaxf(mA, __shfl_xor(mA, s, 32));
            mB = fmaxf(mB, __shfl_xor(mB, s, 32));
        }
        float sA = 0.f, sB = 0.f;
#pragma unroll
        for (int j = 0; j < 4; ++j) {
            sA += __expf(accA[j] - mA);
            sB += __expf(accB[j] - mB);
        }
#pragma unroll
        for (int s = 1; s < 32; s <<= 1) {
            sA += __shfl_xor(sA, s, 32);
            sB += __shfl_xor(sB, s, 32);
        }
        float lA = mA + __logf(sA);
        float lB = mB + __logf(sB);
        float* outA = h + (size_t)(base + nA) * F;
        float* outB = h + (size_t)(base + nB) * F;
#pragma unroll
        for (int j = 0; j < 4; ++j) {
            outA[lane + 32 * j] = accA[j] - lA;
            outB[lane + 32 * j] = accB[j] - lB;
        }
    }
}

// ---------------- launch ----------------

extern "C" void kernel_launch(void* const* d_in, const int* in_sizes, int n_in,
                              void* d_out, int out_size, void* d_ws, size_t ws_size,
                              hipStream_t stream) {
    const float* x = (const float*)d_in[0];
    const float* W = (const float*)d_in[1];
    const float* b = (const float*)d_in[2];
    const int* edge = (const int*)d_in[3];
    const int* row = edge;             // source nodes j
    const int* col = edge + N_EDGES;   // target nodes i
    float* out = (float*)d_out;

    // workspace layout (element offsets, all 4B)
    int*   cnt     = (int*)d_ws;                      // 100k
    int*   fill    = cnt + 102400;                    // 100k
    int*   rowptr  = fill + 102400;                   // 100k+1
    int*   bsum    = rowptr + 102400;                 // 391
    float* dinv    = (float*)(bsum + 1024);           // 100k
    int*   csr_src = (int*)(dinv + 102400);           // 800k
    float* csr_w   = (float*)(csr_src + 819200);      // 800k
    float* h1      = csr_w + 819200;                  // 12.8M

    int nb_nodes = (N_NODES + 255) / 256;
    int nb_edges = (N_EDGES + 255) / 256;

    k_zero<<<(204800 + 255) / 256, 256, 0, stream>>>(cnt, 204800);   // cnt + fill
    k_hist<<<nb_edges, 256, 0, stream>>>(col, cnt);
    k_dinv<<<nb_nodes, 256, 0, stream>>>(cnt, dinv);
    k_scan1<<<SCAN_BLOCKS, 256, 0, stream>>>(cnt, rowptr, bsum);
    k_scan2<<<1, 512, 0, stream>>>(bsum);
    k_scan3<<<nb_nodes, 256, 0, stream>>>(rowptr, bsum);
    k_fill<<<nb_edges, 256, 0, stream>>>(row, col, rowptr, fill, dinv, csr_src, csr_w);

    int gb = (N_NODES * 64 + 255) / 256;   // one wave64 per node
    k_gather<<<gb, 256, 0, stream>>>(rowptr, csr_src, csr_w, dinv, x, h1);
    k_gather<<<gb, 256, 0, stream>>>(rowptr, csr_src, csr_w, dinv, h1, out);
    k_gemm_lsm<<<512, 256, 0, stream>>>(out, W, b);
}

// Round 3
// 337.070 us; speedup vs baseline: 8.7124x; 1.2135x over previous
//
#include <hip/hip_runtime.h>
#include <math.h>

#define N_NODES 100000
#define N_EDGES 800000
#define F 128
#define SCAN_BLOCKS ((N_NODES + 255) / 256)   // 391

typedef __attribute__((ext_vector_type(8))) short short8;
typedef __attribute__((ext_vector_type(4))) float floatx4;

__device__ __forceinline__ unsigned short f2bf(float f) {
    unsigned u = __float_as_uint(f);
    u += 0x7fffu + ((u >> 16) & 1u);          // round-to-nearest-even
    return (unsigned short)(u >> 16);
}
__device__ __forceinline__ float bf_lo(unsigned u) { return __uint_as_float(u << 16); }
__device__ __forceinline__ float bf_hi(unsigned u) { return __uint_as_float(u & 0xffff0000u); }
__device__ __forceinline__ unsigned pack2(float a, float b) {
    return (unsigned)f2bf(a) | ((unsigned)f2bf(b) << 16);
}

// ---------------- CSR build ----------------

__global__ void k_zero(int* __restrict__ p, int n) {
    int i = blockIdx.x * blockDim.x + threadIdx.x;
    if (i < n) p[i] = 0;
}

__global__ void k_hist(const int* __restrict__ col, int* __restrict__ cnt) {
    int e = blockIdx.x * blockDim.x + threadIdx.x;
    if (e < N_EDGES) atomicAdd(&cnt[col[e]], 1);
}

__global__ void k_dinv(const int* __restrict__ cnt, float* __restrict__ dinv) {
    int i = blockIdx.x * blockDim.x + threadIdx.x;
    if (i < N_NODES) dinv[i] = rsqrtf((float)cnt[i] + 1.0f);  // +1 self-loop
}

__global__ void k_scan1(const int* __restrict__ cnt, int* __restrict__ rowptr,
                        int* __restrict__ bsum) {
    __shared__ int s[256];
    int t = threadIdx.x, i = blockIdx.x * 256 + t;
    int v = (i < N_NODES) ? cnt[i] : 0;
    s[t] = v; __syncthreads();
#pragma unroll
    for (int off = 1; off < 256; off <<= 1) {
        int u = (t >= off) ? s[t - off] : 0;
        __syncthreads();
        s[t] += u; __syncthreads();
    }
    if (i < N_NODES) rowptr[i] = s[t] - v;      // exclusive
    if (t == 255) bsum[blockIdx.x] = s[255];
}

__global__ void k_scan2(int* __restrict__ bsum) {
    __shared__ int s[512];
    int t = threadIdx.x;
    int v = (t < SCAN_BLOCKS) ? bsum[t] : 0;
    s[t] = v; __syncthreads();
#pragma unroll
    for (int off = 1; off < 512; off <<= 1) {
        int u = (t >= off) ? s[t - off] : 0;
        __syncthreads();
        s[t] += u; __syncthreads();
    }
    if (t < SCAN_BLOCKS) bsum[t] = s[t] - v;    // exclusive
}

__global__ void k_scan3(int* __restrict__ rowptr, const int* __restrict__ bsum) {
    int i = blockIdx.x * blockDim.x + threadIdx.x;
    if (i < N_NODES) rowptr[i] += bsum[i >> 8];
    if (i == 0) rowptr[N_NODES] = N_EDGES;
}

__global__ void k_fill(const int* __restrict__ row, const int* __restrict__ col,
                       const int* __restrict__ rowptr, int* __restrict__ fill,
                       const float* __restrict__ dinv,
                       int* __restrict__ csr_src, float* __restrict__ csr_w) {
    int e = blockIdx.x * blockDim.x + threadIdx.x;
    if (e >= N_EDGES) return;
    int r = row[e], c = col[e];
    int pos = rowptr[c] + atomicAdd(&fill[c], 1);
    csr_src[pos] = r;
    csr_w[pos] = dinv[r] * dinv[c];
}

// ---------------- fp32 -> bf16 conversion ----------------

__global__ void k_tobf16(const float4* __restrict__ x, uint2* __restrict__ xb, int n4) {
    int i = blockIdx.x * blockDim.x + threadIdx.x;
    if (i < n4) {
        float4 v = x[i];
        uint2 o; o.x = pack2(v.x, v.y); o.y = pack2(v.z, v.w);
        xb[i] = o;
    }
}

// ---------------- propagation: bf16 gather, one wave64 per node ----------------

__global__ __launch_bounds__(256) void k_gather_bf16(const int* __restrict__ rowptr,
                                                     const int* __restrict__ csr_src,
                                                     const float* __restrict__ csr_w,
                                                     const float* __restrict__ dinv,
                                                     const unsigned* __restrict__ src,
                                                     unsigned* __restrict__ dst) {
    int node = (blockIdx.x * blockDim.x + threadIdx.x) >> 6;
    int lane = threadIdx.x & 63;
    if (node >= N_NODES) return;
    float s = dinv[node], ss = s * s;
    unsigned u = src[(size_t)node * 64 + lane];     // row = 64 uints (128 bf16)
    float ax = ss * bf_lo(u), ay = ss * bf_hi(u);   // self-loop term
    int e = rowptr[node], end = rowptr[node + 1];
    for (; e + 2 <= end; e += 2) {
        int r0 = csr_src[e], r1 = csr_src[e + 1];
        float w0 = csr_w[e], w1 = csr_w[e + 1];
        unsigned u0 = src[(size_t)r0 * 64 + lane];
        unsigned u1 = src[(size_t)r1 * 64 + lane];
        ax = fmaf(w0, bf_lo(u0), ax); ay = fmaf(w0, bf_hi(u0), ay);
        ax = fmaf(w1, bf_lo(u1), ax); ay = fmaf(w1, bf_hi(u1), ay);
    }
    if (e < end) {
        int r0 = csr_src[e]; float w0 = csr_w[e];
        unsigned u0 = src[(size_t)r0 * 64 + lane];
        ax = fmaf(w0, bf_lo(u0), ax); ay = fmaf(w0, bf_hi(u0), ay);
    }
    dst[(size_t)node * 64 + lane] = pack2(ax, ay);
}

// ---------------- MFMA GEMM + bias + log_softmax ----------------
// out[n,o] = lsm( h[n,:] @ W[o,:] + b[o] ).  A = h (bf16), B = W^T (bf16).
// Wave computes 16 nodes x 128 outs: 8 N-tiles x 4 K-steps of 16x16x32 MFMA.
// B-frags staged once per persistent block into 128 VGPRs (no LDS).

__global__ __launch_bounds__(256) void k_gemm_lsm_mfma(const unsigned short* __restrict__ h,
                                                       const float* __restrict__ W,
                                                       const float* __restrict__ b,
                                                       float* __restrict__ out) {
    int lane = threadIdx.x & 63;
    int wave = threadIdx.x >> 6;
    int m = lane & 15, quad = lane >> 4;

    // B fragment: lane holds B[k=quad*8+j][n=m] = W[16t+m][ks*32+quad*8+j]
    short8 bfr[8][4];
    float bv[8];
#pragma unroll
    for (int t = 0; t < 8; ++t) {
        bv[t] = b[16 * t + m];
        const float* wr = W + (size_t)(16 * t + m) * 128;
#pragma unroll
        for (int ks = 0; ks < 4; ++ks) {
            const float* wp = wr + ks * 32 + quad * 8;
            short8 v;
#pragma unroll
            for (int j = 0; j < 8; ++j) v[j] = (short)f2bf(wp[j]);
            bfr[t][ks] = v;
        }
    }

    const int ngroups = (N_NODES + 63) / 64;        // 1563 groups of 64 nodes
    for (int g = blockIdx.x; g < ngroups; g += gridDim.x) {
        int gbase = g * 64 + wave * 16;
        int nodeA = gbase + m;
        int node_c = nodeA < N_NODES ? nodeA : N_NODES - 1;
        short8 a[4];                                 // A[m][k=quad*8+j], per kstep
#pragma unroll
        for (int ks = 0; ks < 4; ++ks)
            a[ks] = *(const short8*)(h + (size_t)node_c * 128 + ks * 32 + quad * 8);
        floatx4 acc[8];
#pragma unroll
        for (int t = 0; t < 8; ++t) acc[t] = (floatx4){bv[t], bv[t], bv[t], bv[t]};
#pragma unroll
        for (int ks = 0; ks < 4; ++ks)
#pragma unroll
            for (int t = 0; t < 8; ++t)
                acc[t] = __builtin_amdgcn_mfma_f32_16x16x32_bf16(a[ks], bfr[t][ks], acc[t], 0, 0, 0);

        // D layout: row = gbase + quad*4 + r, col = 16t + m
#pragma unroll
        for (int r = 0; r < 4; ++r) {
            float mx = acc[0][r];
#pragma unroll
            for (int t = 1; t < 8; ++t) mx = fmaxf(mx, acc[t][r]);
#pragma unroll
            for (int msk = 1; msk < 16; msk <<= 1) mx = fmaxf(mx, __shfl_xor(mx, msk));
            float sm = 0.f;
#pragma unroll
            for (int t = 0; t < 8; ++t) sm += __expf(acc[t][r] - mx);
#pragma unroll
            for (int msk = 1; msk < 16; msk <<= 1) sm += __shfl_xor(sm, msk);
            float l = mx + __logf(sm);
            int rown = gbase + quad * 4 + r;
            if (rown < N_NODES) {
                float* op = out + (size_t)rown * 128 + m;
#pragma unroll
                for (int t = 0; t < 8; ++t) op[16 * t] = acc[t][r] - l;
            }
        }
    }
}

// ---------------- launch ----------------

extern "C" void kernel_launch(void* const* d_in, const int* in_sizes, int n_in,
                              void* d_out, int out_size, void* d_ws, size_t ws_size,
                              hipStream_t stream) {
    const float* x = (const float*)d_in[0];
    const float* W = (const float*)d_in[1];
    const float* b = (const float*)d_in[2];
    const int* edge = (const int*)d_in[3];
    const int* row = edge;             // source nodes j
    const int* col = edge + N_EDGES;   // target nodes i
    float* out = (float*)d_out;

    // workspace layout (4B word offsets)
    int*      cnt     = (int*)d_ws;                   // 100k
    int*      fill    = cnt + 102400;                 // 100k
    int*      rowptr  = fill + 102400;                // 100k+1
    int*      bsum    = rowptr + 102400;              // 391
    float*    dinv    = (float*)(bsum + 1024);        // 100k
    int*      csr_src = (int*)(dinv + 102400);        // 800k
    float*    csr_w   = (float*)(csr_src + 819200);   // 800k
    unsigned* xb      = (unsigned*)(csr_w + 819200);  // 6.4M uints = 12.8M bf16
    unsigned* h1b     = xb + 6400000;                 // 6.4M uints
    unsigned* h2b     = xb;                           // reuse: xb dead after hop 1

    int nb_nodes = (N_NODES + 255) / 256;
    int nb_edges = (N_EDGES + 255) / 256;

    k_zero<<<(204800 + 255) / 256, 256, 0, stream>>>(cnt, 204800);   // cnt + fill
    k_hist<<<nb_edges, 256, 0, stream>>>(col, cnt);
    k_dinv<<<nb_nodes, 256, 0, stream>>>(cnt, dinv);
    k_scan1<<<SCAN_BLOCKS, 256, 0, stream>>>(cnt, rowptr, bsum);
    k_scan2<<<1, 512, 0, stream>>>(bsum);
    k_scan3<<<nb_nodes, 256, 0, stream>>>(rowptr, bsum);
    k_fill<<<nb_edges, 256, 0, stream>>>(row, col, rowptr, fill, dinv, csr_src, csr_w);

    int n4 = N_NODES * F / 4;                        // 3.2M float4 groups
    k_tobf16<<<(n4 + 255) / 256, 256, 0, stream>>>((const float4*)x, (uint2*)xb, n4);

    int gb = (N_NODES * 64 + 255) / 256;             // one wave64 per node
    k_gather_bf16<<<gb, 256, 0, stream>>>(rowptr, csr_src, csr_w, dinv, xb, h1b);
    k_gather_bf16<<<gb, 256, 0, stream>>>(rowptr, csr_src, csr_w, dinv, h1b, h2b);

    k_gemm_lsm_mfma<<<512, 256, 0, stream>>>((const unsigned short*)h2b, W, b, out);
}

// Round 4
// 323.803 us; speedup vs baseline: 9.0694x; 1.0410x over previous
//
#include <hip/hip_runtime.h>
#include <math.h>

#define N_NODES 100000
#define N_EDGES 800000
#define F 128
#define SCAN_BLOCKS ((N_NODES + 255) / 256)   // 391

typedef __attribute__((ext_vector_type(8))) short short8;
typedef __attribute__((ext_vector_type(4))) float floatx4;

__device__ __forceinline__ unsigned short f2bf(float f) {
    unsigned u = __float_as_uint(f);
    u += 0x7fffu + ((u >> 16) & 1u);          // round-to-nearest-even
    return (unsigned short)(u >> 16);
}
__device__ __forceinline__ float bf_lo(unsigned u) { return __uint_as_float(u << 16); }
__device__ __forceinline__ float bf_hi(unsigned u) { return __uint_as_float(u & 0xffff0000u); }
__device__ __forceinline__ unsigned pack2(float a, float b) {
    return (unsigned)f2bf(a) | ((unsigned)f2bf(b) << 16);
}

// ---------------- CSR build ----------------

__global__ void k_zero(int* __restrict__ p, int n) {
    int i = blockIdx.x * blockDim.x + threadIdx.x;
    if (i < n) p[i] = 0;
}

__global__ void k_hist(const int* __restrict__ col, int* __restrict__ cnt) {
    int e = blockIdx.x * blockDim.x + threadIdx.x;
    if (e < N_EDGES) atomicAdd(&cnt[col[e]], 1);
}

// block-local exclusive scan of cnt -> rowptr, block totals -> bsum; fused dinv
__global__ void k_scan1(const int* __restrict__ cnt, int* __restrict__ rowptr,
                        int* __restrict__ bsum, float* __restrict__ dinv) {
    __shared__ int s[256];
    int t = threadIdx.x, i = blockIdx.x * 256 + t;
    int v = (i < N_NODES) ? cnt[i] : 0;
    if (i < N_NODES) dinv[i] = rsqrtf((float)v + 1.0f);   // +1 self-loop
    s[t] = v; __syncthreads();
#pragma unroll
    for (int off = 1; off < 256; off <<= 1) {
        int u = (t >= off) ? s[t - off] : 0;
        __syncthreads();
        s[t] += u; __syncthreads();
    }
    if (i < N_NODES) rowptr[i] = s[t] - v;      // exclusive
    if (t == 255) bsum[blockIdx.x] = s[255];
}

__global__ void k_scan2(int* __restrict__ bsum) {
    __shared__ int s[512];
    int t = threadIdx.x;
    int v = (t < SCAN_BLOCKS) ? bsum[t] : 0;
    s[t] = v; __syncthreads();
#pragma unroll
    for (int off = 1; off < 512; off <<= 1) {
        int u = (t >= off) ? s[t - off] : 0;
        __syncthreads();
        s[t] += u; __syncthreads();
    }
    if (t < SCAN_BLOCKS) bsum[t] = s[t] - v;    // exclusive
}

__global__ void k_scan3(int* __restrict__ rowptr, const int* __restrict__ bsum) {
    int i = blockIdx.x * blockDim.x + threadIdx.x;
    if (i < N_NODES) rowptr[i] += bsum[i >> 8];
    if (i == 0) rowptr[N_NODES] = N_EDGES;
}

__global__ void k_fill(const int* __restrict__ row, const int* __restrict__ col,
                       const int* __restrict__ rowptr, int* __restrict__ fill,
                       const float* __restrict__ dinv,
                       int* __restrict__ csr_src, float* __restrict__ csr_w) {
    int e = blockIdx.x * blockDim.x + threadIdx.x;
    if (e >= N_EDGES) return;
    int r = row[e], c = col[e];
    int pos = rowptr[c] + atomicAdd(&fill[c], 1);
    csr_src[pos] = r;
    csr_w[pos] = dinv[r] * dinv[c];
}

// ---------------- hop 1: gather from fp32 x, write bf16; 4-edge pipelined ----------------

__global__ __launch_bounds__(256) void k_gather_f32(const int* __restrict__ rowptr,
                                                    const int* __restrict__ csr_src,
                                                    const float* __restrict__ csr_w,
                                                    const float* __restrict__ dinv,
                                                    const float* __restrict__ x,
                                                    unsigned* __restrict__ dst) {
    int node = (blockIdx.x * blockDim.x + threadIdx.x) >> 6;
    int lane = threadIdx.x & 63;
    if (node >= N_NODES) return;
    const float2* s2 = (const float2*)x;       // row = 64 float2
    float s = dinv[node], ss = s * s;
    float2 v = s2[(size_t)node * 64 + lane];
    float ax = ss * v.x, ay = ss * v.y;        // self-loop term
    int e = rowptr[node], end = rowptr[node + 1];
    for (; e + 4 <= end; e += 4) {             // 4 row-loads in flight
        int r0 = csr_src[e], r1 = csr_src[e + 1], r2 = csr_src[e + 2], r3 = csr_src[e + 3];
        float w0 = csr_w[e], w1 = csr_w[e + 1], w2 = csr_w[e + 2], w3 = csr_w[e + 3];
        float2 u0 = s2[(size_t)r0 * 64 + lane];
        float2 u1 = s2[(size_t)r1 * 64 + lane];
        float2 u2 = s2[(size_t)r2 * 64 + lane];
        float2 u3 = s2[(size_t)r3 * 64 + lane];
        ax = fmaf(w0, u0.x, ax); ay = fmaf(w0, u0.y, ay);
        ax = fmaf(w1, u1.x, ax); ay = fmaf(w1, u1.y, ay);
        ax = fmaf(w2, u2.x, ax); ay = fmaf(w2, u2.y, ay);
        ax = fmaf(w3, u3.x, ax); ay = fmaf(w3, u3.y, ay);
    }
    for (; e < end; ++e) {
        int r0 = csr_src[e]; float w0 = csr_w[e];
        float2 u0 = s2[(size_t)r0 * 64 + lane];
        ax = fmaf(w0, u0.x, ax); ay = fmaf(w0, u0.y, ay);
    }
    dst[(size_t)node * 64 + lane] = pack2(ax, ay);
}

// ---------------- hop 2: bf16 gather, 4-edge pipelined ----------------

__global__ __launch_bounds__(256) void k_gather_bf16(const int* __restrict__ rowptr,
                                                     const int* __restrict__ csr_src,
                                                     const float* __restrict__ csr_w,
                                                     const float* __restrict__ dinv,
                                                     const unsigned* __restrict__ src,
                                                     unsigned* __restrict__ dst) {
    int node = (blockIdx.x * blockDim.x + threadIdx.x) >> 6;
    int lane = threadIdx.x & 63;
    if (node >= N_NODES) return;
    float s = dinv[node], ss = s * s;
    unsigned u = src[(size_t)node * 64 + lane];     // row = 64 uints (128 bf16)
    float ax = ss * bf_lo(u), ay = ss * bf_hi(u);   // self-loop term
    int e = rowptr[node], end = rowptr[node + 1];
    for (; e + 4 <= end; e += 4) {
        int r0 = csr_src[e], r1 = csr_src[e + 1], r2 = csr_src[e + 2], r3 = csr_src[e + 3];
        float w0 = csr_w[e], w1 = csr_w[e + 1], w2 = csr_w[e + 2], w3 = csr_w[e + 3];
        unsigned u0 = src[(size_t)r0 * 64 + lane];
        unsigned u1 = src[(size_t)r1 * 64 + lane];
        unsigned u2 = src[(size_t)r2 * 64 + lane];
        unsigned u3 = src[(size_t)r3 * 64 + lane];
        ax = fmaf(w0, bf_lo(u0), ax); ay = fmaf(w0, bf_hi(u0), ay);
        ax = fmaf(w1, bf_lo(u1), ax); ay = fmaf(w1, bf_hi(u1), ay);
        ax = fmaf(w2, bf_lo(u2), ax); ay = fmaf(w2, bf_hi(u2), ay);
        ax = fmaf(w3, bf_lo(u3), ax); ay = fmaf(w3, bf_hi(u3), ay);
    }
    for (; e < end; ++e) {
        int r0 = csr_src[e]; float w0 = csr_w[e];
        unsigned u0 = src[(size_t)r0 * 64 + lane];
        ax = fmaf(w0, bf_lo(u0), ax); ay = fmaf(w0, bf_hi(u0), ay);
    }
    dst[(size_t)node * 64 + lane] = pack2(ax, ay);
}

// ---------------- MFMA GEMM + bias + log_softmax ----------------

__global__ __launch_bounds__(256) void k_gemm_lsm_mfma(const unsigned short* __restrict__ h,
                                                       const float* __restrict__ W,
                                                       const float* __restrict__ b,
                                                       float* __restrict__ out) {
    int lane = threadIdx.x & 63;
    int wave = threadIdx.x >> 6;
    int m = lane & 15, quad = lane >> 4;

    // B fragment: lane holds B[k=quad*8+j][n=m] = W[16t+m][ks*32+quad*8+j]
    short8 bfr[8][4];
    float bv[8];
#pragma unroll
    for (int t = 0; t < 8; ++t) {
        bv[t] = b[16 * t + m];
        const float* wr = W + (size_t)(16 * t + m) * 128;
#pragma unroll
        for (int ks = 0; ks < 4; ++ks) {
            const float* wp = wr + ks * 32 + quad * 8;
            short8 v;
#pragma unroll
            for (int j = 0; j < 8; ++j) v[j] = (short)f2bf(wp[j]);
            bfr[t][ks] = v;
        }
    }

    const int ngroups = (N_NODES + 63) / 64;        // 1563 groups of 64 nodes
    for (int g = blockIdx.x; g < ngroups; g += gridDim.x) {
        int gbase = g * 64 + wave * 16;
        int nodeA = gbase + m;
        int node_c = nodeA < N_NODES ? nodeA : N_NODES - 1;
        short8 a[4];
#pragma unroll
        for (int ks = 0; ks < 4; ++ks)
            a[ks] = *(const short8*)(h + (size_t)node_c * 128 + ks * 32 + quad * 8);
        floatx4 acc[8];
#pragma unroll
        for (int t = 0; t < 8; ++t) acc[t] = (floatx4){bv[t], bv[t], bv[t], bv[t]};
#pragma unroll
        for (int ks = 0; ks < 4; ++ks)
#pragma unroll
            for (int t = 0; t < 8; ++t)
                acc[t] = __builtin_amdgcn_mfma_f32_16x16x32_bf16(a[ks], bfr[t][ks], acc[t], 0, 0, 0);

        // D layout: row = gbase + quad*4 + r, col = 16t + m
#pragma unroll
        for (int r = 0; r < 4; ++r) {
            float mx = acc[0][r];
#pragma unroll
            for (int t = 1; t < 8; ++t) mx = fmaxf(mx, acc[t][r]);
#pragma unroll
            for (int msk = 1; msk < 16; msk <<= 1) mx = fmaxf(mx, __shfl_xor(mx, msk));
            float sm = 0.f;
#pragma unroll
            for (int t = 0; t < 8; ++t) sm += __expf(acc[t][r] - mx);
#pragma unroll
            for (int msk = 1; msk < 16; msk <<= 1) sm += __shfl_xor(sm, msk);
            float l = mx + __logf(sm);
            int rown = gbase + quad * 4 + r;
            if (rown < N_NODES) {
                float* op = out + (size_t)rown * 128 + m;
#pragma unroll
                for (int t = 0; t < 8; ++t) op[16 * t] = acc[t][r] - l;
            }
        }
    }
}

// ---------------- launch ----------------

extern "C" void kernel_launch(void* const* d_in, const int* in_sizes, int n_in,
                              void* d_out, int out_size, void* d_ws, size_t ws_size,
                              hipStream_t stream) {
    const float* x = (const float*)d_in[0];
    const float* W = (const float*)d_in[1];
    const float* b = (const float*)d_in[2];
    const int* edge = (const int*)d_in[3];
    const int* row = edge;             // source nodes j
    const int* col = edge + N_EDGES;   // target nodes i
    float* out = (float*)d_out;

    // workspace layout (4B word offsets)
    int*      cnt     = (int*)d_ws;                   // 100k
    int*      fill    = cnt + 102400;                 // 100k
    int*      rowptr  = fill + 102400;                // 100k+1
    int*      bsum    = rowptr + 102400;              // 391
    float*    dinv    = (float*)(bsum + 1024);        // 100k
    int*      csr_src = (int*)(dinv + 102400);        // 800k
    float*    csr_w   = (float*)(csr_src + 819200);   // 800k
    unsigned* h1b     = (unsigned*)(csr_w + 819200);  // 6.4M uints = 12.8M bf16
    unsigned* h2b     = h1b + 6400000;                // 6.4M uints

    int nb_edges = (N_EDGES + 255) / 256;

    k_zero<<<(204800 + 255) / 256, 256, 0, stream>>>(cnt, 204800);   // cnt + fill
    k_hist<<<nb_edges, 256, 0, stream>>>(col, cnt);
    k_scan1<<<SCAN_BLOCKS, 256, 0, stream>>>(cnt, rowptr, bsum, dinv);
    k_scan2<<<1, 512, 0, stream>>>(bsum);
    k_scan3<<<SCAN_BLOCKS, 256, 0, stream>>>(rowptr, bsum);
    k_fill<<<nb_edges, 256, 0, stream>>>(row, col, rowptr, fill, dinv, csr_src, csr_w);

    int gb = (N_NODES * 64 + 255) / 256;             // one wave64 per node
    k_gather_f32<<<gb, 256, 0, stream>>>(rowptr, csr_src, csr_w, dinv, x, h1b);
    k_gather_bf16<<<gb, 256, 0, stream>>>(rowptr, csr_src, csr_w, dinv, h1b, h2b);

    k_gemm_lsm_mfma<<<512, 256, 0, stream>>>((const unsigned short*)h2b, W, b, out);
}

// Round 5
// 317.195 us; speedup vs baseline: 9.2583x; 1.0208x over previous
//
#include <hip/hip_runtime.h>
#include <math.h>

#define N_NODES 100000
#define N_EDGES 800000
#define F 128
#define SCAN_BLOCKS ((N_NODES + 255) / 256)   // 391

typedef __attribute__((ext_vector_type(8))) short short8;
typedef __attribute__((ext_vector_type(4))) float floatx4;

__device__ __forceinline__ unsigned short f2bf(float f) {
    unsigned u = __float_as_uint(f);
    u += 0x7fffu + ((u >> 16) & 1u);          // round-to-nearest-even
    return (unsigned short)(u >> 16);
}
__device__ __forceinline__ float bf_lo(unsigned u) { return __uint_as_float(u << 16); }
__device__ __forceinline__ float bf_hi(unsigned u) { return __uint_as_float(u & 0xffff0000u); }
__device__ __forceinline__ unsigned pack2(float a, float b) {
    return (unsigned)f2bf(a) | ((unsigned)f2bf(b) << 16);
}

// ---------------- prep: zero cnt + convert x to bf16 ----------------

__global__ void k_prep(const float4* __restrict__ x, uint2* __restrict__ xb,
                       int* __restrict__ cnt) {
    int i = blockIdx.x * blockDim.x + threadIdx.x;
    if (i < N_NODES) cnt[i] = 0;
    if (i < N_NODES * (F / 4)) {               // 3.2M float4 -> uint2 (4 bf16)
        float4 v = x[i];
        uint2 o; o.x = pack2(v.x, v.y); o.y = pack2(v.z, v.w);
        xb[i] = o;
    }
}

// ---------------- CSR build ----------------

__global__ void k_hist(const int* __restrict__ col, int* __restrict__ cnt) {
    int e = blockIdx.x * blockDim.x + threadIdx.x;
    if (e < N_EDGES) atomicAdd(&cnt[col[e]], 1);
}

// block-local exclusive scan of cnt -> rowptr, block totals -> bsum; fused dinv
__global__ void k_scan1(const int* __restrict__ cnt, int* __restrict__ rowptr,
                        int* __restrict__ bsum, float* __restrict__ dinv) {
    __shared__ int s[256];
    int t = threadIdx.x, i = blockIdx.x * 256 + t;
    int v = (i < N_NODES) ? cnt[i] : 0;
    if (i < N_NODES) dinv[i] = rsqrtf((float)v + 1.0f);   // +1 self-loop
    s[t] = v; __syncthreads();
#pragma unroll
    for (int off = 1; off < 256; off <<= 1) {
        int u = (t >= off) ? s[t - off] : 0;
        __syncthreads();
        s[t] += u; __syncthreads();
    }
    if (i < N_NODES) rowptr[i] = s[t] - v;      // exclusive
    if (t == 255) bsum[blockIdx.x] = s[255];
}

__global__ void k_scan2(int* __restrict__ bsum) {
    __shared__ int s[512];
    int t = threadIdx.x;
    int v = (t < SCAN_BLOCKS) ? bsum[t] : 0;
    s[t] = v; __syncthreads();
#pragma unroll
    for (int off = 1; off < 512; off <<= 1) {
        int u = (t >= off) ? s[t - off] : 0;
        __syncthreads();
        s[t] += u; __syncthreads();
    }
    if (t < SCAN_BLOCKS) bsum[t] = s[t] - v;    // exclusive
}

__global__ void k_scan3(int* __restrict__ rowptr, const int* __restrict__ bsum) {
    int i = blockIdx.x * blockDim.x + threadIdx.x;
    if (i < N_NODES) rowptr[i] += bsum[i >> 8];
    if (i == 0) rowptr[N_NODES] = N_EDGES;
}

// fill CSR; consumes cnt (atomicSub), writes interleaved {src, weight_bits}
__global__ void k_fill(const int* __restrict__ row, const int* __restrict__ col,
                       const int* __restrict__ rowptr, int* __restrict__ cnt,
                       const float* __restrict__ dinv, uint2* __restrict__ csr2) {
    int e = blockIdx.x * blockDim.x + threadIdx.x;
    if (e >= N_EDGES) return;
    int r = row[e], c = col[e];
    int pos = rowptr[c] + atomicSub(&cnt[c], 1) - 1;
    uint2 o; o.x = (unsigned)r; o.y = __float_as_uint(dinv[r] * dinv[c]);
    csr2[pos] = o;
}

// ---------------- propagation: bf16 gather, 2 nodes/wave, 4-deep predicated ----------------
// Row = 32 uint2 (128 bf16). Half-wave (32 lanes x 8B) covers one row.
// 8 row-loads in flight per wave (2 nodes x 4-unroll).

__global__ __launch_bounds__(256) void k_hop(const int* __restrict__ rowptr,
                                             const uint2* __restrict__ csr2,
                                             const float* __restrict__ dinv,
                                             const uint2* __restrict__ src,
                                             uint2* __restrict__ dst) {
    int wv = (blockIdx.x * blockDim.x + threadIdx.x) >> 6;
    int lane = threadIdx.x & 63;
    int half = lane >> 5, off = lane & 31;
    int node = wv * 2 + half;                       // 50k waves exact, node < N
    if (node >= N_NODES) return;
    float s = dinv[node], ss = s * s;
    uint2 u = src[(size_t)node * 32 + off];
    float a0 = ss * bf_lo(u.x), a1 = ss * bf_hi(u.x);
    float a2 = ss * bf_lo(u.y), a3 = ss * bf_hi(u.y);
    int e = rowptr[node], end = rowptr[node + 1];   // uniform within half-wave
    while (__ballot(e < end)) {
#pragma unroll
        for (int j = 0; j < 4; ++j) {
            bool p = (e + j) < end;
            uint2 ew = p ? csr2[e + j] : (uint2){0u, 0u};
            float w = __uint_as_float(ew.y);        // 0 when masked
            uint2 v = p ? src[(size_t)ew.x * 32 + off] : (uint2){0u, 0u};
            a0 = fmaf(w, bf_lo(v.x), a0); a1 = fmaf(w, bf_hi(v.x), a1);
            a2 = fmaf(w, bf_lo(v.y), a2); a3 = fmaf(w, bf_hi(v.y), a3);
        }
        e += 4;
    }
    uint2 o; o.x = pack2(a0, a1); o.y = pack2(a2, a3);
    dst[(size_t)node * 32 + off] = o;
}

// ---------------- MFMA GEMM + bias + log_softmax ----------------

__global__ __launch_bounds__(256) void k_gemm_lsm_mfma(const unsigned short* __restrict__ h,
                                                       const float* __restrict__ W,
                                                       const float* __restrict__ b,
                                                       float* __restrict__ out) {
    int lane = threadIdx.x & 63;
    int wave = threadIdx.x >> 6;
    int m = lane & 15, quad = lane >> 4;

    // B fragment: lane holds B[k=quad*8+j][n=m] = W[16t+m][ks*32+quad*8+j]
    short8 bfr[8][4];
    float bv[8];
#pragma unroll
    for (int t = 0; t < 8; ++t) {
        bv[t] = b[16 * t + m];
        const float* wr = W + (size_t)(16 * t + m) * 128;
#pragma unroll
        for (int ks = 0; ks < 4; ++ks) {
            const float* wp = wr + ks * 32 + quad * 8;
            short8 v;
#pragma unroll
            for (int j = 0; j < 8; ++j) v[j] = (short)f2bf(wp[j]);
            bfr[t][ks] = v;
        }
    }

    const int ngroups = (N_NODES + 63) / 64;        // 1563 groups of 64 nodes
    for (int g = blockIdx.x; g < ngroups; g += gridDim.x) {
        int gbase = g * 64 + wave * 16;
        int nodeA = gbase + m;
        int node_c = nodeA < N_NODES ? nodeA : N_NODES - 1;
        short8 a[4];
#pragma unroll
        for (int ks = 0; ks < 4; ++ks)
            a[ks] = *(const short8*)(h + (size_t)node_c * 128 + ks * 32 + quad * 8);
        floatx4 acc[8];
#pragma unroll
        for (int t = 0; t < 8; ++t) acc[t] = (floatx4){bv[t], bv[t], bv[t], bv[t]};
#pragma unroll
        for (int ks = 0; ks < 4; ++ks)
#pragma unroll
            for (int t = 0; t < 8; ++t)
                acc[t] = __builtin_amdgcn_mfma_f32_16x16x32_bf16(a[ks], bfr[t][ks], acc[t], 0, 0, 0);

        // D layout: row = gbase + quad*4 + r, col = 16t + m
#pragma unroll
        for (int r = 0; r < 4; ++r) {
            float mx = acc[0][r];
#pragma unroll
            for (int t = 1; t < 8; ++t) mx = fmaxf(mx, acc[t][r]);
#pragma unroll
            for (int msk = 1; msk < 16; msk <<= 1) mx = fmaxf(mx, __shfl_xor(mx, msk));
            float sm = 0.f;
#pragma unroll
            for (int t = 0; t < 8; ++t) sm += __expf(acc[t][r] - mx);
#pragma unroll
            for (int msk = 1; msk < 16; msk <<= 1) sm += __shfl_xor(sm, msk);
            float l = mx + __logf(sm);
            int rown = gbase + quad * 4 + r;
            if (rown < N_NODES) {
                float* op = out + (size_t)rown * 128 + m;
#pragma unroll
                for (int t = 0; t < 8; ++t) op[16 * t] = acc[t][r] - l;
            }
        }
    }
}

// ---------------- launch ----------------

extern "C" void kernel_launch(void* const* d_in, const int* in_sizes, int n_in,
                              void* d_out, int out_size, void* d_ws, size_t ws_size,
                              hipStream_t stream) {
    const float* x = (const float*)d_in[0];
    const float* W = (const float*)d_in[1];
    const float* b = (const float*)d_in[2];
    const int* edge = (const int*)d_in[3];
    const int* row = edge;             // source nodes j
    const int* col = edge + N_EDGES;   // target nodes i
    float* out = (float*)d_out;

    // workspace layout (4B word offsets)
    int*   cnt     = (int*)d_ws;                      // 100k
    int*   rowptr  = cnt + 102400;                    // 100k+1
    int*   bsum    = rowptr + 102400;                 // 391
    float* dinv    = (float*)(bsum + 1024);           // 100k
    uint2* csr2    = (uint2*)(dinv + 102400);         // 800k uint2 = 6.4MB
    uint2* xb      = csr2 + 819200;                   // 3.2M uint2 = 25.6MB
    uint2* h1b     = xb + 3276800;                    // 3.2M uint2
    uint2* h2b     = h1b + 3276800;                   // 3.2M uint2

    int nb_edges = (N_EDGES + 255) / 256;
    int nb_prep = (N_NODES * (F / 4) + 255) / 256;    // 12500

    k_prep<<<nb_prep, 256, 0, stream>>>((const float4*)x, xb, cnt);
    k_hist<<<nb_edges, 256, 0, stream>>>(col, cnt);
    k_scan1<<<SCAN_BLOCKS, 256, 0, stream>>>(cnt, rowptr, bsum, dinv);
    k_scan2<<<1, 512, 0, stream>>>(bsum);
    k_scan3<<<SCAN_BLOCKS, 256, 0, stream>>>(rowptr, bsum);
    k_fill<<<nb_edges, 256, 0, stream>>>(row, col, rowptr, cnt, dinv, csr2);

    int hop_blocks = (N_NODES / 2 * 64) / 256;        // 12500: one wave per 2 nodes
    k_hop<<<hop_blocks, 256, 0, stream>>>(rowptr, csr2, dinv, xb, h1b);
    k_hop<<<hop_blocks, 256, 0, stream>>>(rowptr, csr2, dinv, h1b, h2b);

    k_gemm_lsm_mfma<<<512, 256, 0, stream>>>((const unsigned short*)h2b, W, b, out);
}